// Round 10
// baseline (479.457 us; speedup 1.0000x reference)
//
#include <hip/hip_runtime.h>
#include <hip/hip_bf16.h>

// Problem constants
#define B_DIM   512
#define IN_DIM  4096
#define OUT_DIM 11008
#define PB      (B_DIM * OUT_DIM)   // one partial buffer (fp32 elems)

typedef __bf16 bf16x4 __attribute__((ext_vector_type(4)));
typedef __bf16 bf16x8 __attribute__((ext_vector_type(8)));
typedef float  floatx4 __attribute__((ext_vector_type(4)));

// ---------------------------------------------------------------------------
// Pass 1: x fp32 -> bf16
// ---------------------------------------------------------------------------
__global__ __launch_bounds__(256) void conv_x_kernel(
    const float* __restrict__ x, __bf16* __restrict__ xb) {
  int idx = blockIdx.x * blockDim.x + threadIdx.x;
  float4 v = ((const float4*)x)[idx];
  bf16x4 o;
  o[0] = (__bf16)v.x; o[1] = (__bf16)v.y; o[2] = (__bf16)v.z; o[3] = (__bf16)v.w;
  ((bf16x4*)xb)[idx] = o;
}

// ---------------------------------------------------------------------------
// Pass 2: fused QINS-decode + GEMM, v9.
// Model from v2/v6/v7 triangulation: time ∝ LDS bytes (1152 B/krow -> 214-216
// us; 1.5x bytes -> 318 us; conflicts/barriers irrelevant: v2 11M@214 vs
// v7 0@216). Fix: cut LDS bytes per OUTPUT via a square tile.
//  - BM=128 x BN=128 x BK=32, 4 waves 2x2, wave-tile 64x64, acc 4x4:
//    LDS/krow/block = 1536 B for 2x the outputs (12 B/krow/col vs v7's 18).
//    Total LDS traffic 3.25 GB -> 2.16 GB.
//  - split-K=2 (kh-half = 2048 k = 64 tiles) restores grid to 688 blocks;
//    fp32 partials to workspace; tiny reduce applies (p0+p1+bias)*scale.
//  - LDS 32 KB + launch_bounds(256,3) -> 3 blocks/CU -> all 688 co-resident.
//  - v7's proven pieces kept verbatim: one __syncthreads per tile (drains
//    loads issued a full body earlier), B global->reg->decode->ds_write
//    (coalesced), A via chunk-XOR pre-swizzled global_load_lds source,
//    slot = chunk ^ (row&3) on both arrays (floor-level bank spread).
// ---------------------------------------------------------------------------
__device__ __forceinline__ void gl_lds16(const void* g, void* l) {
  __builtin_amdgcn_global_load_lds(
      (const __attribute__((address_space(1))) void*)g,
      (__attribute__((address_space(3))) void*)l, 16, 0, 0);
}

// w = sign * exp(lmin + (255 - s)/254 * (lmax - lmin)); sign-bit XOR
// (bit-exact to *(+-1): verified v5/v6/v7 passed)
__device__ __forceinline__ float dec1f(int s, int g, float lmin, float slope) {
  float e = __expf(fmaf((float)(255 - s), slope, lmin));
  return __uint_as_float(__float_as_uint(e) ^ ((unsigned)g & 0x80000000u));
}

__device__ __forceinline__ bf16x8 dec8(int4 sl, int4 sh, int4 gl, int4 gh,
                                       float lmin, float slope) {
  bf16x8 w;
  w[0] = (__bf16)dec1f(sl.x, gl.x, lmin, slope);
  w[1] = (__bf16)dec1f(sl.y, gl.y, lmin, slope);
  w[2] = (__bf16)dec1f(sl.z, gl.z, lmin, slope);
  w[3] = (__bf16)dec1f(sl.w, gl.w, lmin, slope);
  w[4] = (__bf16)dec1f(sh.x, gh.x, lmin, slope);
  w[5] = (__bf16)dec1f(sh.y, gh.y, lmin, slope);
  w[6] = (__bf16)dec1f(sh.z, gh.z, lmin, slope);
  w[7] = (__bf16)dec1f(sh.w, gh.w, lmin, slope);
  return w;
}

__global__ __launch_bounds__(256, 3) void fused_qins_gemm_kernel(
    const __bf16* __restrict__ A,      // 512 x 4096 bf16 (pre-converted x)
    const int* __restrict__ stored,    // 11008 x 4096 int32 in [1,255]
    const int* __restrict__ sign,      // 11008 x 4096 int32 +-1
    const float* __restrict__ logmin, const float* __restrict__ logmax,
    float* __restrict__ part) {        // 2 x 512 x 11008 fp32 partials
  constexpr int K = IN_DIM, N = OUT_DIM;
  constexpr int BK = 32;
  constexpr int NT = 2048 / BK;        // 64 k-tiles per K-half

  __shared__ __align__(16) __bf16 sA[2][128 * BK];  // 2 x 8 KB
  __shared__ __align__(16) __bf16 sB[2][128 * BK];  // 2 x 8 KB  (32 KB total)

  const int tid  = threadIdx.x;
  const int lane = tid & 63;
  const int wave = tid >> 6;
  const int wm   = (wave >> 1) * 64;   // wave M offset (0/64)
  const int wn   = (wave & 1) * 64;    // wave N offset (0/64)
  const int m16  = lane & 15;
  const int q    = lane >> 4;          // 0..3

  // 688 = 2 kh x 4 bm x 86 bn. XCD swizzle (688 = 8x86, bijective); within
  // a chunk, the 4 bm-blocks of a (kh,bn) panel are consecutive -> same XCD
  // (stored/sign panel reuse x4 in that XCD's L2).
  const int wg  = blockIdx.x;                 // 0..687
  const int g   = (wg & 7) * 86 + (wg >> 3);  // bijective
  const int kh  = g / 344;
  const int rem = g % 344;
  const int bm0 = (rem & 3) * 128;
  const int bn0 = (rem >> 2) * 128;
  const int kbase = kh * 2048;

  const float lmin  = logmin[0];
  const float slope = (logmax[0] - lmin) * (1.0f / 254.0f);

  // ---- A staging: 2 gl_lds instrs; chunk-XOR on the GLOBAL source ----
  // Rows are 64 B (32 elems = 4 chunks of 8). Instr j, thread tid -> LDS
  // (row = j*64 + (tid>>2), slot = tid&3); slot holds chunk slot^(row&3);
  // (row&3) = (tid>>2)&3, invariant across j.
  const int arow = tid >> 2;                  // 0..63
  const int achk = (tid & 3) ^ (arow & 3);
  const __bf16* gA0 = A + (size_t)(bm0 + arow) * K + kbase + achk * 8;
  const __bf16* gA1 = gA0 + (size_t)64 * K;   // rows +64: (row&3) unchanged

  // ---- B staging: 16 ints/thread (row tid>>1, chunk pair bq2,bq2+1) ----
  const int rB  = tid >> 1;                   // 0..127
  const int bq2 = (tid & 1) * 2;              // chunks {bq2, bq2+1}
  const int* pS = stored + (size_t)(bn0 + rB) * K + kbase + bq2 * 8;
  const int* pG = sign   + (size_t)(bn0 + rB) * K + kbase + bq2 * 8;
  const int wOff0 = rB * BK + ((bq2       ^ (rB & 3)) * 8);
  const int wOff1 = rB * BK + (((bq2 + 1) ^ (rB & 3)) * 8);

  // frag read slot: chunk q at row with (row&3) = (m16&3)
  const int slotB = (q ^ (m16 & 3)) * 8;

  floatx4 acc[4][4] = {};

  // ---- Prologue: B(0)->sB[0]; A(0)->sA[0]; B(1)->regs; barrier ----
  int4 s0, s1, s2, s3, g0, g1, g2, g3;
  s0 = *(const int4*)(pS);     s1 = *(const int4*)(pS + 4);
  s2 = *(const int4*)(pS + 8); s3 = *(const int4*)(pS + 12);
  g0 = *(const int4*)(pG);     g1 = *(const int4*)(pG + 4);
  g2 = *(const int4*)(pG + 8); g3 = *(const int4*)(pG + 12);
  *(bf16x8*)&sB[0][wOff0] = dec8(s0, s1, g0, g1, lmin, slope);
  *(bf16x8*)&sB[0][wOff1] = dec8(s2, s3, g2, g3, lmin, slope);
  gl_lds16(gA0, &sA[0][tid * 8]);
  gl_lds16(gA1, &sA[0][2048 + tid * 8]);
  s0 = *(const int4*)(pS + BK);     s1 = *(const int4*)(pS + BK + 4);
  s2 = *(const int4*)(pS + BK + 8); s3 = *(const int4*)(pS + BK + 12);
  g0 = *(const int4*)(pG + BK);     g1 = *(const int4*)(pG + BK + 4);
  g2 = *(const int4*)(pG + BK + 8); g3 = *(const int4*)(pG + BK + 12);
  __syncthreads();   // compiler drains vmcnt+lgkm: tile 0 fully resident

  // Body t: decode B(t+1)->sB[c^1]; issue A(t+1); load B(t+2) regs;
  // ds_read frags(t); 16 MFMA; one __syncthreads (drains loads issued a
  // full body earlier). v7-proven structure.
  for (int t = 0; t < NT; ++t) {
    const int c = t & 1;

    *(bf16x8*)&sB[c ^ 1][wOff0] = dec8(s0, s1, g0, g1, lmin, slope);
    *(bf16x8*)&sB[c ^ 1][wOff1] = dec8(s2, s3, g2, g3, lmin, slope);

    const int ktA = ((t + 1 < NT) ? (t + 1) : 0) * BK;
    gl_lds16(gA0 + ktA, &sA[c ^ 1][tid * 8]);
    gl_lds16(gA1 + ktA, &sA[c ^ 1][2048 + tid * 8]);

    const int ktB = ((t + 2 < NT) ? (t + 2) : 0) * BK;
    s0 = *(const int4*)(pS + ktB);     s1 = *(const int4*)(pS + ktB + 4);
    s2 = *(const int4*)(pS + ktB + 8); s3 = *(const int4*)(pS + ktB + 12);
    g0 = *(const int4*)(pG + ktB);     g1 = *(const int4*)(pG + ktB + 4);
    g2 = *(const int4*)(pG + ktB + 8); g3 = *(const int4*)(pG + ktB + 12);

    bf16x8 afr[4], bfr[4];
#pragma unroll
    for (int mi = 0; mi < 4; ++mi)
      afr[mi] = *(const bf16x8*)&sA[c][(wm + mi * 16 + m16) * BK + slotB];
#pragma unroll
    for (int ni = 0; ni < 4; ++ni)
      bfr[ni] = *(const bf16x8*)&sB[c][(wn + ni * 16 + m16) * BK + slotB];

#pragma unroll
    for (int mi = 0; mi < 4; ++mi)
#pragma unroll
      for (int ni = 0; ni < 4; ++ni)
        acc[mi][ni] = __builtin_amdgcn_mfma_f32_16x16x32_bf16(
            afr[mi], bfr[ni], acc[mi][ni], 0, 0, 0);

    __syncthreads();
  }

  // Epilogue: raw fp32 partial (scale/bias applied in reduce).
  // C/D layout: col = lane&15, row = q*4 + reg  [m89]
  float* p = part + (size_t)kh * PB;
#pragma unroll
  for (int ni = 0; ni < 4; ++ni) {
    const int col = bn0 + wn + ni * 16 + m16;
#pragma unroll
    for (int mi = 0; mi < 4; ++mi) {
#pragma unroll
      for (int r = 0; r < 4; ++r) {
        const int row = bm0 + wm + mi * 16 + q * 4 + r;
        p[(size_t)row * N + col] = acc[mi][ni][r];
      }
    }
  }
}

// ---------------------------------------------------------------------------
// Pass 3: out = (p0 + p1 + bias) * scale    (float4, 11008 % 4 == 0)
// ---------------------------------------------------------------------------
__global__ __launch_bounds__(256) void reduce_kernel(
    const float* __restrict__ part, const float* __restrict__ scale,
    const float* __restrict__ bias, float* __restrict__ out) {
  const int i4  = blockIdx.x * blockDim.x + threadIdx.x;  // float4 index
  const int col = (i4 % (OUT_DIM / 4)) * 4;
  float4 a = ((const float4*)part)[i4];
  float4 b = ((const float4*)(part + PB))[i4];
  float4 sc = *(const float4*)(scale + col);
  float4 bb = *(const float4*)(bias + col);
  float4 o;
  o.x = (a.x + b.x + bb.x) * sc.x;
  o.y = (a.y + b.y + bb.y) * sc.y;
  o.z = (a.z + b.z + bb.z) * sc.z;
  o.w = (a.w + b.w + bb.w) * sc.w;
  ((float4*)out)[i4] = o;
}

// ---------------------------------------------------------------------------
extern "C" void kernel_launch(void* const* d_in, const int* in_sizes, int n_in,
                              void* d_out, int out_size, void* d_ws, size_t ws_size,
                              hipStream_t stream) {
  const float* x      = (const float*)d_in[0];
  const int*   stored = (const int*)d_in[1];
  const int*   sign   = (const int*)d_in[2];
  const float* logmin = (const float*)d_in[3];
  const float* logmax = (const float*)d_in[4];
  const float* scale  = (const float*)d_in[5];
  const float* bias   = (const float*)d_in[6];
  float* out = (float*)d_out;

  float*  wsP = (float*)d_ws;                     // 2 x 22.5 MB partials
  __bf16* wsX = (__bf16*)(wsP + 2 * (size_t)PB);  // 4 MB bf16 x

  conv_x_kernel<<<2048, 256, 0, stream>>>(x, wsX);
  // 2 kh x 4 bm x 86 bn = 688 blocks (XCD-swizzled), all co-resident @3/CU
  fused_qins_gemm_kernel<<<688, 256, 0, stream>>>(
      wsX, stored, sign, logmin, logmax, wsP);
  // 512*11008/4 float4s / 256 = 5504 blocks
  reduce_kernel<<<PB / 4 / 256, 256, 0, stream>>>(wsP, scale, bias, out);
}